// Round 1
// baseline (82.985 us; speedup 1.0000x reference)
//
#include <hip/hip_runtime.h>
#include <hip/hip_bf16.h>

// MaxPoolingMatching: out[b,l,p] = max_m cos( s1[b,l,:]∘k[p,:], s2[b,m,:]∘k[p,:] )
// B=16, L=256, D=256, P=20.
//
// v5: FUSED single kernel — prep2 deleted (it was ~40µs of the 82.6µs total:
// top-5 rocprof dispatches are all 43µs fills, so both kernels were <42.6µs
// each, i.e. prep was grossly disproportionate to its ~13MB/84MFLOP of work).
// Each block is now self-sufficient, zero workspace:
//   - X2 = bf16(s2[b]) built from raw f32 (swizzled ds_writes; XCD-grouped
//     block swizzle makes the 16x redundant f32 reads per b L2-hits),
//   - rn2 via in-block MFMA: bf16(s2^2) staged through the X1 region in four
//     64-row groups against register bf16(k^2) B-frags; wave w ends up holding
//     rn2 for exactly its epilogue rows m∈[32w,32w+32) (per-p col via 8 shfl),
//   - rn1 factored OUT of X1 (max_m(acc*rn1*rn2) = rn1*max_m(acc*rn2)):
//     X1 = bf16(s1*k^2); rn1 computed once by wave 0 (MFMA over bf16(s1^2))
//     and applied at the 64-thread output through a 256B alias-region slice.
// LDS = 131072 + 32768 = 163840 B exactly; 256 blocks x 512 threads (1/CU).

#define B_DIM 16
#define L_DIM 256
#define D_DIM 256
#define P_DIM 20
#define EPS 1e-12f

typedef __attribute__((ext_vector_type(8))) __bf16 bf16x8;
typedef __attribute__((ext_vector_type(4))) float f32x4;

union BV { bf16x8 v; unsigned short u[8]; };

__device__ __forceinline__ unsigned short f2bf(float x) {
  unsigned int u = __float_as_uint(x);
  u += 0x7fffu + ((u >> 16) & 1u);   // RNE
  return (unsigned short)(u >> 16);
}

__global__ __launch_bounds__(512, 1)
void mpm_fused(const float* __restrict__ s1, const float* __restrict__ s2,
               const float* __restrict__ kg, float* __restrict__ outg) {
  __shared__ __align__(16) unsigned short X2[256 * 256];  // 128KB bf16(s2), swizzled
  __shared__ __align__(16) unsigned short X1[64 * 256];   // 32KB: Q(s^2) / X1(s1*k^2) / epilogue alias
  float* WoutF  = (float*)X1;          // f32 [0,512): per-wave maxes
  float* Rn1col = ((float*)X1) + 512;  // f32 [512,576): rn1 column for current p

  const int tid = threadIdx.x, lane = tid & 63, wave = tid >> 6;  // 8 waves
  const int lr = lane & 15, q = lane >> 4;

  // XCD-grouping swizzle: XCD i gets logical blocks 32i..32i+31 = 2 full b's,
  // so the 16 blocks sharing a b read its f32 s2 from that XCD's L2.
  const int bid = (int)((blockIdx.x >> 3) + (blockIdx.x & 7) * 32);
  const int pgi = bid & 3, lt = (bid >> 2) & 3, b = bid >> 4;
  const int l0 = lt * 64;

  // ---- issue the s1 tile loads early (consumed in phase C) ----
  float4 s1f[8];
  {
    const float* s1b = s1 + ((size_t)b * L_DIM + l0) * D_DIM;
    #pragma unroll
    for (int i = 0; i < 8; ++i)
      s1f[i] = *(const float4*)(s1b + (size_t)(i * 8 + wave) * D_DIM + lane * 4);
  }

  // ---- issue first s2 group loads ----
  const float* s2b = s2 + (size_t)b * L_DIM * D_DIM;
  float4 sv[8];
  #pragma unroll
  for (int i = 0; i < 8; ++i)
    sv[i] = *(const float4*)(s2b + (size_t)(i * 8 + wave) * D_DIM + lane * 4);

  // ---- B-fragments bf16(k^2) for the norm MFMAs (rows lr>=5 zeroed) ----
  // frag layout (verified in prep2): row = lane&15 (=p), k = ks*32 + q*8 + e
  bf16x8 bk2[8];
  {
    const bool ok = (lr < 5);
    const float* kr = kg + (size_t)(pgi * 5 + lr) * D_DIM + q * 8;
    #pragma unroll
    for (int ks = 0; ks < 8; ++ks) {
      BV t;
      if (ok) {
        float4 a = *(const float4*)(kr + ks * 32);
        float4 c = *(const float4*)(kr + ks * 32 + 4);
        t.u[0] = f2bf(a.x * a.x); t.u[1] = f2bf(a.y * a.y);
        t.u[2] = f2bf(a.z * a.z); t.u[3] = f2bf(a.w * a.w);
        t.u[4] = f2bf(c.x * c.x); t.u[5] = f2bf(c.y * c.y);
        t.u[6] = f2bf(c.z * c.z); t.u[7] = f2bf(c.w * c.w);
      } else {
        #pragma unroll
        for (int e = 0; e < 8; ++e) t.u[e] = 0;
      }
      bk2[ks] = t.v;
    }
  }

  // ---- phase B: stage X2 + per-group Q = bf16(s2^2); rn2 MFMA per group ----
  // wave w owns group g = w>>1, local tiles (w&1)*2..+1  =>  m in [32w, 32w+32)
  f32x4 an2[2] = {{0.f, 0.f, 0.f, 0.f}, {0.f, 0.f, 0.f, 0.f}};
  #pragma unroll
  for (int g = 0; g < 4; ++g) {
    #pragma unroll
    for (int i = 0; i < 8; ++i) {
      const int r = g * 64 + i * 8 + wave, rl = r & 63;
      const int colsw = (((lane >> 1) ^ (r & 31)) << 3) + ((lane & 1) << 2);
      unsigned int c0 = ((unsigned int)f2bf(sv[i].y) << 16) | f2bf(sv[i].x);
      unsigned int c1 = ((unsigned int)f2bf(sv[i].w) << 16) | f2bf(sv[i].z);
      *(uint2*)&X2[r * 256 + colsw] = make_uint2(c0, c1);
      unsigned int q0 = ((unsigned int)f2bf(sv[i].y * sv[i].y) << 16) | f2bf(sv[i].x * sv[i].x);
      unsigned int q1 = ((unsigned int)f2bf(sv[i].w * sv[i].w) << 16) | f2bf(sv[i].z * sv[i].z);
      *(uint2*)&X1[rl * 256 + colsw] = make_uint2(q0, q1);
    }
    if (g < 3) {   // prefetch next group: reg-destined loads survive the barriers
      #pragma unroll
      for (int i = 0; i < 8; ++i)
        sv[i] = *(const float4*)(s2b + (size_t)((g + 1) * 64 + i * 8 + wave) * D_DIM + lane * 4);
    }
    __syncthreads();           // group-g Q complete
    if ((wave >> 1) == g) {
      #pragma unroll
      for (int t = 0; t < 2; ++t) {
        const int row = ((wave & 1) * 2 + t) * 16 + lr;
        #pragma unroll
        for (int ks = 0; ks < 8; ++ks) {
          const int cc = ks * 4 + q;
          bf16x8 a = *(const bf16x8*)&X1[row * 256 + ((cc ^ (row & 31)) << 3)];
          an2[t] = __builtin_amdgcn_mfma_f32_16x16x32_bf16(a, bk2[ks], an2[t], 0, 0, 0);
        }
      }
    }
    __syncthreads();           // MFMA reads done before Q is overwritten
  }

  // ---- phase C: s1 -> s1r regs + Q = bf16(s1^2); rn1 MFMA in wave 0 ----
  uint2 s1r[8];
  #pragma unroll
  for (int i = 0; i < 8; ++i) {
    const int row = i * 8 + wave;
    const int colsw = (((lane >> 1) ^ (row & 31)) << 3) + ((lane & 1) << 2);
    unsigned int c0 = ((unsigned int)f2bf(s1f[i].y) << 16) | f2bf(s1f[i].x);
    unsigned int c1 = ((unsigned int)f2bf(s1f[i].w) << 16) | f2bf(s1f[i].z);
    s1r[i] = make_uint2(c0, c1);
    unsigned int q0 = ((unsigned int)f2bf(s1f[i].y * s1f[i].y) << 16) | f2bf(s1f[i].x * s1f[i].x);
    unsigned int q1 = ((unsigned int)f2bf(s1f[i].w * s1f[i].w) << 16) | f2bf(s1f[i].z * s1f[i].z);
    *(uint2*)&X1[row * 256 + colsw] = make_uint2(q0, q1);
  }
  __syncthreads();
  float rn1v[4][4];            // wave 0 only: rn1[l = t*16+q*4+r][p = lr]
  if (wave == 0) {
    #pragma unroll
    for (int t = 0; t < 4; ++t) {
      f32x4 a4 = {0.f, 0.f, 0.f, 0.f};
      const int row = t * 16 + lr;
      #pragma unroll
      for (int ks = 0; ks < 8; ++ks) {
        const int cc = ks * 4 + q;
        bf16x8 a = *(const bf16x8*)&X1[row * 256 + ((cc ^ (row & 31)) << 3)];
        a4 = __builtin_amdgcn_mfma_f32_16x16x32_bf16(a, bk2[ks], a4, 0, 0, 0);
      }
      #pragma unroll
      for (int r = 0; r < 4; ++r) rn1v[t][r] = rsqrtf(fmaxf(a4[r], EPS));
    }
  }
  float rn2v[2][4];            // rn2[m = wave*32 + t*16 + q*4 + r][p = lr]
  #pragma unroll
  for (int t = 0; t < 2; ++t)
    #pragma unroll
    for (int r = 0; r < 4; ++r) rn2v[t][r] = rsqrtf(fmaxf(an2[t][r], EPS));

  // ---- phase D: p-loop ----
  const int mrow0 = wave * 32 + lr, mrow1 = wave * 32 + 16 + lr;
  const int mkey0 = mrow0 & 31,     mkey1 = mrow1 & 31;

  #pragma unroll 1
  for (int pp = 0; pp < 5; ++pp) {
    const int p = pgi * 5 + pp;
    __syncthreads();   // X1 region free (pp=0: rn1-MFMA reads done; pp>0: alias reads done)

    // build X1 = bf16( s1 * k^2 )  (rn1 applied at output instead)
    {
      float4 kv = *(const float4*)(kg + (size_t)p * D_DIM + lane * 4);
      const float k0 = kv.x * kv.x, k1 = kv.y * kv.y, k2 = kv.z * kv.z, k3 = kv.w * kv.w;
      #pragma unroll
      for (int i = 0; i < 8; ++i) {
        const int row = i * 8 + wave;
        float x0 = __uint_as_float(s1r[i].x << 16)         * k0;
        float x1 = __uint_as_float(s1r[i].x & 0xffff0000u) * k1;
        float x2 = __uint_as_float(s1r[i].y << 16)         * k2;
        float x3 = __uint_as_float(s1r[i].y & 0xffff0000u) * k3;
        unsigned int c0 = ((unsigned int)f2bf(x1) << 16) | f2bf(x0);
        unsigned int c1 = ((unsigned int)f2bf(x3) << 16) | f2bf(x2);
        *(uint2*)&X1[row * 256 + (((lane >> 1) ^ (row & 31)) << 3) + ((lane & 1) << 2)] =
            make_uint2(c0, c1);
      }
    }
    __syncthreads();   // X1 visible

    // K-loop: wave computes C[32m x 64l]
    f32x4 acc[2][4];
    #pragma unroll
    for (int mi = 0; mi < 2; ++mi)
      #pragma unroll
      for (int li = 0; li < 4; ++li) acc[mi][li] = (f32x4){0.f, 0.f, 0.f, 0.f};

    #pragma unroll
    for (int ks = 0; ks < 8; ++ks) {
      const int cc = ks * 4 + q;
      bf16x8 a0 = *(const bf16x8*)&X2[mrow0 * 256 + ((cc ^ mkey0) << 3)];
      bf16x8 a1 = *(const bf16x8*)&X2[mrow1 * 256 + ((cc ^ mkey1) << 3)];
      bf16x8 bb[4];
      #pragma unroll
      for (int li = 0; li < 4; ++li) {
        const int l = li * 16 + lr;
        bb[li] = *(const bf16x8*)&X1[l * 256 + ((cc ^ (l & 31)) << 3)];
      }
      #pragma unroll
      for (int li = 0; li < 4; ++li) {
        acc[0][li] = __builtin_amdgcn_mfma_f32_16x16x32_bf16(a0, bb[li], acc[0][li], 0, 0, 0);
        acc[1][li] = __builtin_amdgcn_mfma_f32_16x16x32_bf16(a1, bb[li], acc[1][li], 0, 0, 0);
      }
    }

    // epilogue: C row(reg) = m = wave*32 + mi*16 + q*4 + r ; col(lane) = l = li*16+lr
    // rn2 column pp lives in this wave's lanes (q'=q, lr'=pp) -> 8 bpermutes
    float r2[2][4];
    #pragma unroll
    for (int t = 0; t < 2; ++t)
      #pragma unroll
      for (int r = 0; r < 4; ++r) r2[t][r] = __shfl(rn2v[t][r], q * 16 + pp);

    float v[4];
    #pragma unroll
    for (int li = 0; li < 4; ++li) {
      float t = -3.4e38f;
      #pragma unroll
      for (int r = 0; r < 4; ++r)
        t = fmaxf(t, fmaxf(acc[0][li][r] * r2[0][r], acc[1][li][r] * r2[1][r]));
      t = fmaxf(t, __shfl_xor(t, 16));
      t = fmaxf(t, __shfl_xor(t, 32));
      v[li] = t;
    }

    __syncthreads();   // X1 reads done -> alias region safe
    if (q == 0) {
      #pragma unroll
      for (int li = 0; li < 4; ++li) WoutF[wave * 64 + li * 16 + lr] = v[li];
    }
    if (wave == 0 && lr == pp) {   // 4 lanes (q=0..3) deposit the rn1 column
      #pragma unroll
      for (int t = 0; t < 4; ++t)
        #pragma unroll
        for (int r = 0; r < 4; ++r) Rn1col[t * 16 + q * 4 + r] = rn1v[t][r];
    }
    __syncthreads();   // WoutF + Rn1col visible
    if (tid < 64) {
      float o = WoutF[tid];
      #pragma unroll
      for (int w = 1; w < 8; ++w) o = fmaxf(o, WoutF[w * 64 + tid]);
      outg[((size_t)b * L_DIM + (l0 + tid)) * P_DIM + p] = o * Rn1col[tid];
    }
  }
}

extern "C" void kernel_launch(void* const* d_in, const int* in_sizes, int n_in,
                              void* d_out, int out_size, void* d_ws, size_t ws_size,
                              hipStream_t stream) {
  (void)in_sizes; (void)n_in; (void)out_size; (void)d_ws; (void)ws_size;
  const float* s1 = (const float*)d_in[0];
  const float* s2 = (const float*)d_in[1];
  const float* kg = (const float*)d_in[2];
  float* out = (float*)d_out;

  mpm_fused<<<dim3(256), dim3(512), 0, stream>>>(s1, s2, kg, out);
}